// Round 8
// baseline (5794.425 us; speedup 1.0000x reference)
//
#include <hip/hip_runtime.h>

// MM_LSTM_Age_v2 on MI355X — single fused systolic pipeline.
// k0a/k0b: weight transpose->bf16.  k1: eco xW (full T).
// kP (240 WGs, 1 block/CU, co-resident): rec0(16) + rec1(112, xW fused with
//   Wk in VGPRs) + rec2(112, ts-xW fused, A = hsD*hsA from tagged rings).
//   Cross-WG exchange format: u64 {state tag(hi32), 2xbf16(lo32)}, accessed as
//   16B VOLATILE u32x4 granules (global_*_dwordx4 sc0 sc1: L2-bypass,
//   MALL-coherent, COALESCED — unlike atomics which issue 1 txn per lane).
//   Tag rides with payload in the same 16B store -> single round trip.
// k7/k8: dense head.

#define TT 365
#define RE 4   // eco h ring slots
#define RS 4   // hs (data/att -> ts) ring slots

typedef short bf16x8 __attribute__((ext_vector_type(8)));
typedef float f32x4 __attribute__((ext_vector_type(4)));
typedef unsigned int u32x4 __attribute__((ext_vector_type(4)));
typedef unsigned int u32x2 __attribute__((ext_vector_type(2)));

__device__ __forceinline__ float b2f(unsigned short u) {
  union { unsigned u32; float f; } v; v.u32 = ((unsigned)u) << 16; return v.f;
}
__device__ __forceinline__ unsigned short f2b(float f) {
  union { float f; unsigned u32; } v; v.f = f;
  unsigned u = v.u32;
  u = u + 0x7FFFu + ((u >> 16) & 1u);   // RNE
  return (unsigned short)(u >> 16);
}
__device__ __forceinline__ float sigf(float x) { return 1.0f / (1.0f + __expf(-x)); }
__device__ __forceinline__ float tanh_(float x) { return 2.0f / (1.0f + __expf(-2.0f * x)) - 1.0f; }

// volatile 16B access -> global_load/store_dwordx4 sc0 sc1 (cache-bypass, coalesced)
__device__ __forceinline__ u32x4 vld(const u32x4* p) { return *(const volatile u32x4*)p; }
__device__ __forceinline__ void vst(u32x4* p, u32x4 v) { *(volatile u32x4*)p = v; }
__device__ __forceinline__ unsigned vld32(const unsigned* p) { return *(const volatile unsigned*)p; }
__device__ __forceinline__ void vst32(unsigned* p, unsigned v) { *(volatile unsigned*)p = v; }
__device__ __forceinline__ unsigned pack2(float a, float b) {
  return (unsigned)f2b(a) | ((unsigned)f2b(b) << 16);
}

// ------------------------------------------------ k0a: Wr transpose -> bf16
// wr_swz per (lstm,wg): [kb 8][col 128][ks 32], col = gate*32+hi
__global__ __launch_bounds__(256) void k0a_wr(const float* __restrict__ eco_Wr,
    const float* __restrict__ data_Wr, const float* __restrict__ att_Wr,
    const float* __restrict__ ts_Wr, unsigned short* __restrict__ wr_swz)
{
  __shared__ float ls[32 * 133];
  const int kb = blockIdx.x, wg = blockIdx.y, l = blockIdx.z, tid = threadIdx.x;
  const float* src;
  if (l == 0) src = eco_Wr;
  else if (l < 15) { int d = l - 1; src = ((d & 1) ? att_Wr : data_Wr) + (size_t)(d >> 1) * 262144; }
  else src = ts_Wr + (size_t)(l - 15) * 262144;
  for (int e = tid; e < 4096; e += 256) {
    int ks = e >> 7, col = e & 127;
    int gate = col >> 5, hi = col & 31;
    ls[ks * 133 + col] = src[(size_t)(kb * 32 + ks) * 1024 + gate * 256 + wg * 32 + hi];
  }
  __syncthreads();
  unsigned short* out = wr_swz + (((size_t)l * 8 + wg) * 8 + kb) * 4096;
  for (int e = tid; e < 4096; e += 256) {
    int col = e >> 5, ks = e & 31;
    out[e] = f2b(ls[ks * 133 + col]);
  }
}

// ------------------------------------------------ k0b: Wk transpose -> bf16
// wk layout per lstm: [kb 8][col 1024][ks 32] (data/att use K rows 4..259)
__global__ __launch_bounds__(256) void k0b_wk(const float* __restrict__ data_Wk,
    const float* __restrict__ att_Wk, const float* __restrict__ ts_Wk,
    unsigned short* __restrict__ wk_da, unsigned short* __restrict__ wk_ts)
{
  __shared__ float ls[32 * 261];
  const int cc = blockIdx.x, kb = blockIdx.y, d = blockIdx.z, tid = threadIdx.x;
  const float* src; unsigned short* dst; int roff;
  if (d < 14) { src = ((d & 1) ? att_Wk : data_Wk) + (size_t)(d >> 1) * 266240;
                dst = wk_da + (size_t)d * 262144; roff = 4; }
  else { src = ts_Wk + (size_t)(d - 14) * 262144;
         dst = wk_ts + (size_t)(d - 14) * 262144; roff = 0; }
  for (int e = tid; e < 8192; e += 256) {
    int ks = e >> 8, c2 = e & 255;
    ls[ks * 261 + c2] = src[(size_t)(roff + kb * 32 + ks) * 1024 + cc * 256 + c2];
  }
  __syncthreads();
  for (int e = tid; e < 8192; e += 256) {
    int col2 = e >> 5, ks = e & 31;
    dst[(size_t)kb * 32768 + (cc * 256 + col2) * 32 + ks] = f2b(ls[ks * 261 + col2]);
  }
}

// ------------------------------------------------ k1: eco xW full T
__global__ __launch_bounds__(256) void k1_ecoxw(const float* __restrict__ inputs,
    const float* __restrict__ eco_Wk, const float* __restrict__ eco_b,
    unsigned short* __restrict__ xw_eco)
{
  __shared__ float Asl[64 * 35];
  __shared__ float Bsl[35 * 256];
  const int tg = blockIdx.x, ct = blockIdx.y, tid = threadIdx.x;
  for (int i = tid; i < 64 * 35; i += 256) {
    int b = i / 35, k = i - b * 35;
    int col = (k < 20) ? k : (k + 7);
    Asl[i] = inputs[((size_t)b * TT + tg) * 42 + col];
  }
  for (int i = tid; i < 35 * 256; i += 256) {
    int k = i >> 8, c = i & 255;
    Bsl[i] = eco_Wk[(size_t)k * 1024 + ct * 256 + c];
  }
  __syncthreads();
  const float bias = eco_b[ct * 256 + tid];
  for (int r = 0; r < 64; ++r) {
    float s = bias;
    #pragma unroll
    for (int k = 0; k < 35; ++k) s += Asl[r * 35 + k] * Bsl[k * 256 + tid];
    xw_eco[((size_t)tg * 64 + r) * 1024 + ct * 256 + tid] = f2b(s);
  }
}

// ================================================ kP: full systolic pipeline
// All exchange buffers viewed as u32x4 granules: granule g covers u64 pair
// (2g,2g+1) i.e. bf16 quad, layout [pay0,tag0,pay1,tag1].
// hE:  granules[RE][64 row][64 q]        (eco h)
// hD:  per l1 granules[2][64][64]        (data/att own h)
// hsD/hsA: per br granules[RS][64][64]   (hs streams to ts, tag = t+1)
// h2:  per d granules[2][64][64]         (ts own h)
// hDf[112] (l1*8+colwg), h2f[112] (d*16+sub): lagged overwrite guards.
__global__ __launch_bounds__(256, 1) void kP(
    const unsigned short* __restrict__ wr_swz,
    const unsigned short* __restrict__ wk_da,
    const unsigned short* __restrict__ wk_ts,
    const unsigned short* __restrict__ xw_eco,
    const float* __restrict__ inputs,
    const float* __restrict__ data_Wk, const float* __restrict__ att_Wk,
    const float* __restrict__ data_b, const float* __restrict__ att_b,
    const float* __restrict__ ts_b,
    u32x4* __restrict__ hE,
    u32x4* __restrict__ hD,
    u32x4* __restrict__ hsD,
    u32x4* __restrict__ hsA,
    u32x4* __restrict__ h2,
    unsigned* __restrict__ hDf, unsigned* __restrict__ h2f,
    float* __restrict__ h_last)
{
  __shared__ __align__(16) unsigned char smem[160256];
  const int tid = threadIdx.x;
  const int widx = blockIdx.x;
  const int lane = tid & 63, w = tid >> 6, c = lane & 15, grp = lane >> 4;

  if (widx < 16) {
    // ================= rec0: eco LSTM, 32 batch x 32 hid per WG
    unsigned short* WR = (unsigned short*)smem;             // 81920
    unsigned short* Hs = (unsigned short*)(smem + 81920);   // 20480
    float* zsh = (float*)(smem + 102400);                   // 16896
    float* cst = (float*)(smem + 119296);                   // 4096
    const int wg = widx >> 1, bg = widx & 1;
    const unsigned short* wr_g = wr_swz + (size_t)wg * 32768;
    for (int i = tid * 8; i < 32768; i += 2048) {
      int kb = i >> 12; int rr = i & 4095; int col = rr >> 5; int ks = rr & 31;
      *(uint4*)&WR[(kb * 128 + col) * 40 + ks] = *(const uint4*)&wr_g[i];
    }
    for (int i = tid; i < 1024; i += 256) cst[i] = 0.0f;

    int xoff[16];
    #pragma unroll
    for (int rt = 0; rt < 2; ++rt)
      #pragma unroll
      for (int ct = 0; ct < 2; ++ct)
        #pragma unroll
        for (int rg = 0; rg < 4; ++rg)
          xoff[(rt * 2 + ct) * 4 + rg] =
              (bg * 32 + rt * 16 + grp * 4 + rg) * 1024 + w * 256 + wg * 32 + ct * 16 + c;
    unsigned short xv[16], xn[16];
    #pragma unroll
    for (int i = 0; i < 16; ++i) xv[i] = xw_eco[xoff[i]];
    __syncthreads();

    for (int t = 0; t < TT; ++t) {
      // lagged ring guard: rec1 must have consumed the slot we overwrite
      if (t + 1 > RE && tid < 112) {
        while ((int)vld32(&hDf[tid]) < t + 1 - RE) __builtin_amdgcn_s_sleep(2);
      }
      { // tag-polled gather of own state t (8 granules, rows of this bg)
        const u32x4* hb = hE + (size_t)(t % RE) * 4096;
        u32x4 v[8];
        #pragma unroll
        for (int i = 0; i < 8; ++i) {
          int g = tid + i * 256;
          v[i] = vld(&hb[(bg * 32 + (g >> 6)) * 64 + (g & 63)]);
        }
        const unsigned tagv = (unsigned)t;
        int tries = 0;
        while (true) {
          unsigned pend = 0u;
          #pragma unroll
          for (int i = 0; i < 8; ++i)
            pend |= (v[i].y != tagv || v[i].w != tagv) ? (1u << i) : 0u;
          if (!pend) break;
          if (++tries > 8) __builtin_amdgcn_s_sleep(1);
          #pragma unroll
          for (int i = 0; i < 8; ++i)
            if (pend & (1u << i)) {
              int g = tid + i * 256;
              v[i] = vld(&hb[(bg * 32 + (g >> 6)) * 64 + (g & 63)]);
            }
        }
        #pragma unroll
        for (int i = 0; i < 8; ++i) {
          int g = tid + i * 256, row = g >> 6, q = g & 63;
          u32x2 pv; pv.x = v[i].x; pv.y = v[i].z;
          *(u32x2*)&Hs[((q >> 3) * 32 + row) * 40 + 4 * (q & 7)] = pv;
        }
      }
      __syncthreads();
      f32x4 acc[4];
      #pragma unroll
      for (int i = 0; i < 4; ++i)
        #pragma unroll
        for (int rg = 0; rg < 4; ++rg) acc[i][rg] = b2f(xv[i * 4 + rg]);
      if (t + 1 < TT) {
        const unsigned short* xw1 = xw_eco + (size_t)(t + 1) * 65536;
        #pragma unroll
        for (int i = 0; i < 16; ++i) xn[i] = xw1[xoff[i]];
      }
      #pragma unroll
      for (int kb = 0; kb < 8; ++kb) {
        bf16x8 a0 = *(const bf16x8*)&Hs[(kb * 32 + c) * 40 + grp * 8];
        bf16x8 a1 = *(const bf16x8*)&Hs[(kb * 32 + 16 + c) * 40 + grp * 8];
        bf16x8 b0 = *(const bf16x8*)&WR[(kb * 128 + w * 32 + c) * 40 + grp * 8];
        bf16x8 b1 = *(const bf16x8*)&WR[(kb * 128 + w * 32 + 16 + c) * 40 + grp * 8];
        acc[0] = __builtin_amdgcn_mfma_f32_16x16x32_bf16(a0, b0, acc[0], 0, 0, 0);
        acc[1] = __builtin_amdgcn_mfma_f32_16x16x32_bf16(a0, b1, acc[1], 0, 0, 0);
        acc[2] = __builtin_amdgcn_mfma_f32_16x16x32_bf16(a1, b0, acc[2], 0, 0, 0);
        acc[3] = __builtin_amdgcn_mfma_f32_16x16x32_bf16(a1, b1, acc[3], 0, 0, 0);
      }
      #pragma unroll
      for (int i = 0; i < 4; ++i) {
        int rt = i >> 1, ct = i & 1;
        #pragma unroll
        for (int rg = 0; rg < 4; ++rg)
          zsh[(rt * 16 + grp * 4 + rg) * 132 + w * 32 + ct * 16 + c] = acc[i][rg];
      }
      __syncthreads();
      { // cell update: 1 row x 4 hid, publish one tagged granule
        int row = tid >> 3, hq8 = tid & 7;
        float4 zi = *(const float4*)&zsh[row * 132 +      hq8 * 4];
        float4 zf = *(const float4*)&zsh[row * 132 + 32 + hq8 * 4];
        float4 zg = *(const float4*)&zsh[row * 132 + 64 + hq8 * 4];
        float4 zo = *(const float4*)&zsh[row * 132 + 96 + hq8 * 4];
        float4 c0 = *(const float4*)&cst[row * 32 + hq8 * 4];
        float cn0 = sigf(zf.x) * c0.x + sigf(zi.x) * tanh_(zg.x);
        float cn1 = sigf(zf.y) * c0.y + sigf(zi.y) * tanh_(zg.y);
        float cn2 = sigf(zf.z) * c0.z + sigf(zi.z) * tanh_(zg.z);
        float cn3 = sigf(zf.w) * c0.w + sigf(zi.w) * tanh_(zg.w);
        float hv0 = sigf(zo.x) * tanh_(cn0);
        float hv1 = sigf(zo.y) * tanh_(cn1);
        float hv2 = sigf(zo.z) * tanh_(cn2);
        float hv3 = sigf(zo.w) * tanh_(cn3);
        *(float4*)&cst[row * 32 + hq8 * 4] = make_float4(cn0, cn1, cn2, cn3);
        u32x4 pv; pv.x = pack2(hv0, hv1); pv.y = (unsigned)(t + 1);
        pv.z = pack2(hv2, hv3); pv.w = (unsigned)(t + 1);
        vst(&hE[(size_t)((t + 1) % RE) * 4096 + (bg * 32 + row) * 64 + wg * 8 + hq8], pv);
      }
      __syncthreads();
      #pragma unroll
      for (int i = 0; i < 16; ++i) xv[i] = xn[i];
    }
  } else if (widx < 128) {
    // ================= rec1: data/att LSTM l1, 64 batch x 32 hid, xW fused
    unsigned short* WR = (unsigned short*)smem;             // 81920
    unsigned short* Hs = (unsigned short*)(smem + 81920);   // 40960
    float* zsh = (float*)(smem + 122880);                   // 33792
    float* a_sp = (float*)(smem + 156672);                  // 1024
    float* b_sp = (float*)(smem + 157696);                  // 2048
    float* bias_s = (float*)(smem + 159744);                // 512
    const int q0 = widx - 16, l1 = q0 >> 3, colwg = q0 & 7, br = l1 >> 1;
    const bool act_sig = (l1 & 1);
    const unsigned short* wr_g = wr_swz + ((size_t)(1 + l1) * 8 + colwg) * 32768;
    for (int i = tid * 8; i < 32768; i += 2048) {
      int kb = i >> 12; int rr = i & 4095; int col = rr >> 5; int ks = rr & 31;
      *(uint4*)&WR[(kb * 128 + col) * 40 + ks] = *(const uint4*)&wr_g[i];
    }
    bf16x8 wkf[16];
    const unsigned short* wk = wk_da + (size_t)l1 * 262144;
    #pragma unroll
    for (int kb = 0; kb < 8; ++kb)
      #pragma unroll
      for (int ct = 0; ct < 2; ++ct) {
        int col = w * 256 + colwg * 32 + ct * 16 + c;
        wkf[kb * 2 + ct] = *(const bf16x8*)&wk[kb * 32768 + col * 32 + grp * 8];
      }
    const float* spWk = (act_sig ? att_Wk : data_Wk) + (size_t)br * 266240;
    for (int i = tid; i < 512; i += 256) {
      int j = i >> 7, colL = i & 127;
      int gcol = (colL >> 5) * 256 + colwg * 32 + (colL & 31);
      b_sp[i] = spWk[(size_t)j * 1024 + gcol];
    }
    if (tid < 128) {
      int gcol = (tid >> 5) * 256 + colwg * 32 + (tid & 31);
      bias_s[tid] = (act_sig ? att_b : data_b)[br * 1024 + gcol];
    }
    float creg[8];
    #pragma unroll
    for (int j = 0; j < 8; ++j) creg[j] = 0.0f;
    u32x4* hDl = hD + (size_t)l1 * 2 * 4096;
    u32x4* ring = (act_sig ? hsA : hsD) + (size_t)br * RS * 4096;
    __syncthreads();

    for (int t = 0; t < TT; ++t) {
      // lagged ring guard: rec2 must have consumed the hs slot we overwrite
      if (t + 1 > RS && tid < 16) {
        while ((int)vld32(&h2f[br * 16 + tid]) < t + 1 - RS) __builtin_amdgcn_s_sleep(2);
      }
      if (tid < 64) {
        const float* ip = inputs + ((size_t)tid * TT + t) * 42;
        a_sp[tid * 4 + 0] = ip[20 + br];
        a_sp[tid * 4 + 1] = ip[27];
        a_sp[tid * 4 + 2] = ip[27 + br + 1];
        a_sp[tid * 4 + 3] = ip[27 + br + 8];
      }
      // issue both gathers (16 granules each: full 64 rows x 64 q)
      const u32x4* he = hE + (size_t)((t + 1) % RE) * 4096;
      const u32x4* ho = hDl + (size_t)(t & 1) * 4096;
      u32x4 ve[16], vh[16];
      #pragma unroll
      for (int i = 0; i < 16; ++i) ve[i] = vld(&he[tid + i * 256]);
      #pragma unroll
      for (int i = 0; i < 16; ++i) vh[i] = vld(&ho[tid + i * 256]);
      { // poll eco h tags == t+1
        const unsigned tagv = (unsigned)(t + 1);
        int tries = 0;
        while (true) {
          unsigned pend = 0u;
          #pragma unroll
          for (int i = 0; i < 16; ++i)
            pend |= (ve[i].y != tagv || ve[i].w != tagv) ? (1u << i) : 0u;
          if (!pend) break;
          if (++tries > 8) __builtin_amdgcn_s_sleep(1);
          #pragma unroll
          for (int i = 0; i < 16; ++i)
            if (pend & (1u << i)) ve[i] = vld(&he[tid + i * 256]);
        }
      }
      #pragma unroll
      for (int i = 0; i < 16; ++i) {
        int g = tid + i * 256, row = g >> 6, q = g & 63;
        u32x2 pv; pv.x = ve[i].x; pv.y = ve[i].z;
        *(u32x2*)&Hs[((q >> 3) * 64 + row) * 40 + 4 * (q & 7)] = pv;
      }
      __syncthreads();
      // xW MFMA (A = eco h, B = Wk regs)
      f32x4 acc[8] = {};
      #pragma unroll
      for (int kb = 0; kb < 8; ++kb) {
        bf16x8 a[4];
        #pragma unroll
        for (int rt = 0; rt < 4; ++rt)
          a[rt] = *(const bf16x8*)&Hs[(kb * 64 + rt * 16 + c) * 40 + grp * 8];
        #pragma unroll
        for (int rt = 0; rt < 4; ++rt)
          #pragma unroll
          for (int ct = 0; ct < 2; ++ct)
            acc[rt * 2 + ct] = __builtin_amdgcn_mfma_f32_16x16x32_bf16(a[rt], wkf[kb * 2 + ct], acc[rt * 2 + ct], 0, 0, 0);
      }
      #pragma unroll
      for (int i = 0; i < 8; ++i) {
        int rt = i >> 1, ct2 = i & 1;
        #pragma unroll
        for (int rg = 0; rg < 4; ++rg) {
          int row = rt * 16 + grp * 4 + rg;
          int colL = w * 32 + ct2 * 16 + c;
          acc[i][rg] += bias_s[colL]
                      + a_sp[row * 4 + 0] * b_sp[colL]       + a_sp[row * 4 + 1] * b_sp[128 + colL]
                      + a_sp[row * 4 + 2] * b_sp[256 + colL] + a_sp[row * 4 + 3] * b_sp[384 + colL];
        }
      }
      { // poll own h tags == t (usually instant)
        const unsigned tagv = (unsigned)t;
        int tries = 0;
        while (true) {
          unsigned pend = 0u;
          #pragma unroll
          for (int i = 0; i < 16; ++i)
            pend |= (vh[i].y != tagv || vh[i].w != tagv) ? (1u << i) : 0u;
          if (!pend) break;
          if (++tries > 8) __builtin_amdgcn_s_sleep(1);
          #pragma unroll
          for (int i = 0; i < 16; ++i)
            if (pend & (1u << i)) vh[i] = vld(&ho[tid + i * 256]);
        }
      }
      __syncthreads();                 // everyone done reading Hs (eco h)
      #pragma unroll
      for (int i = 0; i < 16; ++i) {
        int g = tid + i * 256, row = g >> 6, q = g & 63;
        u32x2 pv; pv.x = vh[i].x; pv.y = vh[i].z;
        *(u32x2*)&Hs[((q >> 3) * 64 + row) * 40 + 4 * (q & 7)] = pv;
      }
      __syncthreads();
      // recurrent MFMA (A = own h, B = Wr LDS)
      #pragma unroll
      for (int kb = 0; kb < 8; ++kb) {
        bf16x8 a[4]; bf16x8 b[2];
        #pragma unroll
        for (int rt = 0; rt < 4; ++rt)
          a[rt] = *(const bf16x8*)&Hs[(kb * 64 + rt * 16 + c) * 40 + grp * 8];
        #pragma unroll
        for (int ct = 0; ct < 2; ++ct)
          b[ct] = *(const bf16x8*)&WR[(kb * 128 + w * 32 + ct * 16 + c) * 40 + grp * 8];
        #pragma unroll
        for (int rt = 0; rt < 4; ++rt)
          #pragma unroll
          for (int ct = 0; ct < 2; ++ct)
            acc[rt * 2 + ct] = __builtin_amdgcn_mfma_f32_16x16x32_bf16(a[rt], b[ct], acc[rt * 2 + ct], 0, 0, 0);
      }
      #pragma unroll
      for (int i = 0; i < 8; ++i) {
        int rt = i >> 1, ct2 = i & 1;
        #pragma unroll
        for (int rg = 0; rg < 4; ++rg)
          zsh[(rt * 16 + grp * 4 + rg) * 132 + w * 32 + ct2 * 16 + c] = acc[i][rg];
      }
      __syncthreads();
      { // cell: 2 items x 4 hid; publish own h + hs ring (tag t+1), 1 granule each
        u32x4* hon = hDl + (size_t)((t + 1) & 1) * 4096;
        u32x4* rs = ring + (size_t)(t % RS) * 4096;
        #pragma unroll
        for (int it = 0; it < 2; ++it) {
          int m = tid + it * 256, row = m >> 3, hq8 = m & 7;
          float4 zi = *(const float4*)&zsh[row * 132 +      hq8 * 4];
          float4 zf = *(const float4*)&zsh[row * 132 + 32 + hq8 * 4];
          float4 zg = *(const float4*)&zsh[row * 132 + 64 + hq8 * 4];
          float4 zo = *(const float4*)&zsh[row * 132 + 96 + hq8 * 4];
          float g0 = act_sig ? sigf(zg.x) : tanh_(zg.x);
          float g1 = act_sig ? sigf(zg.y) : tanh_(zg.y);
          float g2 = act_sig ? sigf(zg.z) : tanh_(zg.z);
          float g3 = act_sig ? sigf(zg.w) : tanh_(zg.w);
          float cn0 = sigf(zf.x) * creg[it * 4 + 0] + sigf(zi.x) * g0;
          float cn1 = sigf(zf.y) * creg[it * 4 + 1] + sigf(zi.y) * g1;
          float cn2 = sigf(zf.z) * creg[it * 4 + 2] + sigf(zi.z) * g2;
          float cn3 = sigf(zf.w) * creg[it * 4 + 3] + sigf(zi.w) * g3;
          float hv0 = sigf(zo.x) * (act_sig ? sigf(cn0) : tanh_(cn0));
          float hv1 = sigf(zo.y) * (act_sig ? sigf(cn1) : tanh_(cn1));
          float hv2 = sigf(zo.z) * (act_sig ? sigf(cn2) : tanh_(cn2));
          float hv3 = sigf(zo.w) * (act_sig ? sigf(cn3) : tanh_(cn3));
          creg[it * 4 + 0] = cn0; creg[it * 4 + 1] = cn1;
          creg[it * 4 + 2] = cn2; creg[it * 4 + 3] = cn3;
          u32x4 pv; pv.x = pack2(hv0, hv1); pv.y = (unsigned)(t + 1);
          pv.z = pack2(hv2, hv3); pv.w = (unsigned)(t + 1);
          int gidx = row * 64 + colwg * 8 + hq8;
          vst(&hon[gidx], pv);
          vst(&rs[gidx], pv);
        }
      }
      __syncthreads();
      if (tid == 0) vst32(&hDf[q0], (unsigned)(t + 1));   // lagged guard only
    }
  } else {
    // ================= rec2: ts LSTM d, 32 batch x 32 hid, xW fused
    unsigned short* WR = (unsigned short*)smem;             // 81920
    unsigned short* Hs = (unsigned short*)(smem + 81920);   // 20480
    float* zsh = (float*)(smem + 102400);                   // 16896
    float* bias_s = (float*)(smem + 119296);                // 512
    const int r = widx - 128, d = r >> 4, sub = r & 15, colwg = sub >> 1, bg = sub & 1;
    const unsigned short* wr_g = wr_swz + ((size_t)(15 + d) * 8 + colwg) * 32768;
    for (int i = tid * 8; i < 32768; i += 2048) {
      int kb = i >> 12; int rr = i & 4095; int col = rr >> 5; int ks = rr & 31;
      *(uint4*)&WR[(kb * 128 + col) * 40 + ks] = *(const uint4*)&wr_g[i];
    }
    bf16x8 wkf[16];
    const unsigned short* wk = wk_ts + (size_t)d * 262144;
    #pragma unroll
    for (int kb = 0; kb < 8; ++kb)
      #pragma unroll
      for (int ct = 0; ct < 2; ++ct) {
        int col = w * 256 + colwg * 32 + ct * 16 + c;
        wkf[kb * 2 + ct] = *(const bf16x8*)&wk[kb * 32768 + col * 32 + grp * 8];
      }
    if (tid < 128) {
      int gcol = (tid >> 5) * 256 + colwg * 32 + (tid & 31);
      bias_s[tid] = ts_b[d * 1024 + gcol];
    }
    float creg[4] = {0.0f, 0.0f, 0.0f, 0.0f};
    const u32x4* rD = hsD + (size_t)d * RS * 4096;
    const u32x4* rA = hsA + (size_t)d * RS * 4096;
    u32x4* h2d = h2 + (size_t)d * 2 * 4096;
    __syncthreads();

    for (int t = 0; t < TT; ++t) {
      const u32x4* sd = rD + (size_t)(t % RS) * 4096;
      const u32x4* sa = rA + (size_t)(t % RS) * 4096;
      const u32x4* ho = h2d + (size_t)(t & 1) * 4096;
      u32x4 vd[8], va[8], vh[8];
      int gidx[8];
      #pragma unroll
      for (int i = 0; i < 8; ++i) {
        int g = tid + i * 256;
        gidx[i] = (bg * 32 + (g >> 6)) * 64 + (g & 63);
      }
      #pragma unroll
      for (int i = 0; i < 8; ++i) vd[i] = vld(&sd[gidx[i]]);
      #pragma unroll
      for (int i = 0; i < 8; ++i) va[i] = vld(&sa[gidx[i]]);
      #pragma unroll
      for (int i = 0; i < 8; ++i) vh[i] = vld(&ho[gidx[i]]);
      { // poll hs tags == t+1 (both rings)
        const unsigned tagv = (unsigned)(t + 1);
        int tries = 0;
        while (true) {
          unsigned pend = 0u;
          #pragma unroll
          for (int i = 0; i < 8; ++i) {
            pend |= (vd[i].y != tagv || vd[i].w != tagv) ? (1u << i) : 0u;
            pend |= (va[i].y != tagv || va[i].w != tagv) ? (0x100u << i) : 0u;
          }
          if (!pend) break;
          if (++tries > 8) __builtin_amdgcn_s_sleep(1);
          #pragma unroll
          for (int i = 0; i < 8; ++i) {
            if (pend & (1u << i)) vd[i] = vld(&sd[gidx[i]]);
            if (pend & (0x100u << i)) va[i] = vld(&sa[gidx[i]]);
          }
        }
      }
      #pragma unroll
      for (int i = 0; i < 8; ++i) {  // product -> Hs
        int g = tid + i * 256, row = g >> 6, q = g & 63;
        unsigned d0 = vd[i].x, a0 = va[i].x, d1 = vd[i].z, a1 = va[i].z;
        u32x2 pv;
        pv.x = pack2(b2f((unsigned short)d0) * b2f((unsigned short)a0),
                     b2f((unsigned short)(d0 >> 16)) * b2f((unsigned short)(a0 >> 16)));
        pv.y = pack2(b2f((unsigned short)d1) * b2f((unsigned short)a1),
                     b2f((unsigned short)(d1 >> 16)) * b2f((unsigned short)(a1 >> 16)));
        *(u32x2*)&Hs[((q >> 3) * 32 + row) * 40 + 4 * (q & 7)] = pv;
      }
      __syncthreads();
      f32x4 acc[4] = {};
      #pragma unroll
      for (int kb = 0; kb < 8; ++kb) {
        bf16x8 a0 = *(const bf16x8*)&Hs[(kb * 32 + c) * 40 + grp * 8];
        bf16x8 a1 = *(const bf16x8*)&Hs[(kb * 32 + 16 + c) * 40 + grp * 8];
        acc[0] = __builtin_amdgcn_mfma_f32_16x16x32_bf16(a0, wkf[kb * 2 + 0], acc[0], 0, 0, 0);
        acc[1] = __builtin_amdgcn_mfma_f32_16x16x32_bf16(a0, wkf[kb * 2 + 1], acc[1], 0, 0, 0);
        acc[2] = __builtin_amdgcn_mfma_f32_16x16x32_bf16(a1, wkf[kb * 2 + 0], acc[2], 0, 0, 0);
        acc[3] = __builtin_amdgcn_mfma_f32_16x16x32_bf16(a1, wkf[kb * 2 + 1], acc[3], 0, 0, 0);
      }
      #pragma unroll
      for (int i = 0; i < 4; ++i) {
        int ct2 = i & 1;
        #pragma unroll
        for (int rg = 0; rg < 4; ++rg)
          acc[i][rg] += bias_s[w * 32 + ct2 * 16 + c];
      }
      { // poll own h tags == t (instant)
        const unsigned tagv = (unsigned)t;
        int tries = 0;
        while (true) {
          unsigned pend = 0u;
          #pragma unroll
          for (int i = 0; i < 8; ++i)
            pend |= (vh[i].y != tagv || vh[i].w != tagv) ? (1u << i) : 0u;
          if (!pend) break;
          if (++tries > 8) __builtin_amdgcn_s_sleep(1);
          #pragma unroll
          for (int i = 0; i < 8; ++i)
            if (pend & (1u << i)) vh[i] = vld(&ho[gidx[i]]);
        }
      }
      __syncthreads();
      #pragma unroll
      for (int i = 0; i < 8; ++i) {
        int g = tid + i * 256, row = g >> 6, q = g & 63;
        u32x2 pv; pv.x = vh[i].x; pv.y = vh[i].z;
        *(u32x2*)&Hs[((q >> 3) * 32 + row) * 40 + 4 * (q & 7)] = pv;
      }
      __syncthreads();
      #pragma unroll
      for (int kb = 0; kb < 8; ++kb) {
        bf16x8 a0 = *(const bf16x8*)&Hs[(kb * 32 + c) * 40 + grp * 8];
        bf16x8 a1 = *(const bf16x8*)&Hs[(kb * 32 + 16 + c) * 40 + grp * 8];
        bf16x8 b0 = *(const bf16x8*)&WR[(kb * 128 + w * 32 + c) * 40 + grp * 8];
        bf16x8 b1 = *(const bf16x8*)&WR[(kb * 128 + w * 32 + 16 + c) * 40 + grp * 8];
        acc[0] = __builtin_amdgcn_mfma_f32_16x16x32_bf16(a0, b0, acc[0], 0, 0, 0);
        acc[1] = __builtin_amdgcn_mfma_f32_16x16x32_bf16(a0, b1, acc[1], 0, 0, 0);
        acc[2] = __builtin_amdgcn_mfma_f32_16x16x32_bf16(a1, b0, acc[2], 0, 0, 0);
        acc[3] = __builtin_amdgcn_mfma_f32_16x16x32_bf16(a1, b1, acc[3], 0, 0, 0);
      }
      #pragma unroll
      for (int i = 0; i < 4; ++i) {
        int rt = i >> 1, ct2 = i & 1;
        #pragma unroll
        for (int rg = 0; rg < 4; ++rg)
          zsh[(rt * 16 + grp * 4 + rg) * 132 + w * 32 + ct2 * 16 + c] = acc[i][rg];
      }
      __syncthreads();
      { // cell: 1 row x 4 hid; publish h2 granule
        int row = tid >> 3, hq8 = tid & 7;
        float4 zi = *(const float4*)&zsh[row * 132 +      hq8 * 4];
        float4 zf = *(const float4*)&zsh[row * 132 + 32 + hq8 * 4];
        float4 zg = *(const float4*)&zsh[row * 132 + 64 + hq8 * 4];
        float4 zo = *(const float4*)&zsh[row * 132 + 96 + hq8 * 4];
        float cn0 = sigf(zf.x) * creg[0] + sigf(zi.x) * tanh_(zg.x);
        float cn1 = sigf(zf.y) * creg[1] + sigf(zi.y) * tanh_(zg.y);
        float cn2 = sigf(zf.z) * creg[2] + sigf(zi.z) * tanh_(zg.z);
        float cn3 = sigf(zf.w) * creg[3] + sigf(zi.w) * tanh_(zg.w);
        float hv0 = sigf(zo.x) * tanh_(cn0);
        float hv1 = sigf(zo.y) * tanh_(cn1);
        float hv2 = sigf(zo.z) * tanh_(cn2);
        float hv3 = sigf(zo.w) * tanh_(cn3);
        creg[0] = cn0; creg[1] = cn1; creg[2] = cn2; creg[3] = cn3;
        u32x4 pv; pv.x = pack2(hv0, hv1); pv.y = (unsigned)(t + 1);
        pv.z = pack2(hv2, hv3); pv.w = (unsigned)(t + 1);
        vst(&h2d[(size_t)((t + 1) & 1) * 4096 + (bg * 32 + row) * 64 + colwg * 8 + hq8], pv);
        if (t == TT - 1) {
          *(float4*)&h_last[(size_t)d * 16384 + (bg * 32 + row) * 256 + colwg * 32 + hq8 * 4]
              = make_float4(hv0, hv1, hv2, hv3);
        }
      }
      __syncthreads();
      if (tid == 0) vst32(&h2f[d * 16 + sub], (unsigned)(t + 1));   // lagged guard
    }
  }
}

// ------------------------------------------------ head
__global__ __launch_bounds__(256) void k7_d1(const float* __restrict__ h_last,
    const float* __restrict__ d1_W, const float* __restrict__ d1_b, float* __restrict__ d1o)
{
  __shared__ float Asl[64 * 256];
  __shared__ float Bsl[256 * 64];
  const int nt = blockIdx.x, br = blockIdx.y, tid = threadIdx.x;
  const float* hl = h_last + (size_t)br * 16384;
  for (int i = tid; i < 16384; i += 256) Asl[i] = hl[i];
  const float* wp = d1_W + (size_t)br * 65536 + nt * 64;
  for (int i = tid; i < 16384; i += 256) {
    int k = i >> 6, cl = i & 63;
    Bsl[i] = wp[(size_t)k * 256 + cl];
  }
  __syncthreads();
  const int cl = tid & 63, rq = tid >> 6;
  float s[16];
  const float bias = d1_b[br * 256 + nt * 64 + cl];
  #pragma unroll
  for (int i = 0; i < 16; ++i) s[i] = bias;
  for (int k = 0; k < 256; ++k) {
    float bv = Bsl[k * 64 + cl];
    #pragma unroll
    for (int i = 0; i < 16; ++i) s[i] += Asl[(rq * 16 + i) * 256 + k] * bv;
  }
  #pragma unroll
  for (int i = 0; i < 16; ++i)
    d1o[(size_t)br * 16384 + (rq * 16 + i) * 256 + nt * 64 + cl] = fmaxf(s[i], 0.0f);
}

__global__ __launch_bounds__(256) void k8_head(const float* __restrict__ d1o,
    const float* __restrict__ d2_W, const float* __restrict__ d2_b,
    const float* __restrict__ df_W, const float* __restrict__ df_b,
    const float* __restrict__ inputs, float* __restrict__ out)
{
  __shared__ float Asl[64 * 256];
  __shared__ float Bsl[256 * 64];
  __shared__ float d2sT[64 * 65];
  __shared__ float wfs[68];
  const int br = blockIdx.x, tid = threadIdx.x;
  for (int i = tid; i < 16384; i += 256) Asl[i] = d1o[(size_t)br * 16384 + i];
  for (int i = tid; i < 16384; i += 256) Bsl[i] = d2_W[(size_t)br * 16384 + i];
  if (tid < 67) wfs[tid] = df_W[br * 67 + tid];
  __syncthreads();
  const int cl = tid & 63, rq = tid >> 6;
  float s[16];
  const float bias = d2_b[br * 64 + cl];
  #pragma unroll
  for (int i = 0; i < 16; ++i) s[i] = bias;
  for (int k = 0; k < 256; ++k) {
    float bv = Bsl[k * 64 + cl];
    #pragma unroll
    for (int i = 0; i < 16; ++i) s[i] += Asl[(rq * 16 + i) * 256 + k] * bv;
  }
  #pragma unroll
  for (int i = 0; i < 16; ++i) d2sT[cl * 65 + rq * 16 + i] = fmaxf(s[i], 0.0f);
  __syncthreads();
  if (tid < 64) {
    const int b = tid;
    const float* ip = inputs + ((size_t)b * TT + (TT - 1)) * 42;
    float acc = df_b[br] + ip[20 + br] + ip[27] * wfs[64] + ip[27 + br + 1] * wfs[65]
              + ip[27 + br + 8] * wfs[66];
    #pragma unroll 4
    for (int j = 0; j < 64; ++j) acc += d2sT[j * 65 + b] * wfs[j];
    out[b * 7 + br] = acc;
  }
}

// ------------------------------------------------ host
extern "C" void kernel_launch(void* const* d_in, const int* in_sizes, int n_in,
                              void* d_out, int out_size, void* d_ws, size_t ws_size,
                              hipStream_t stream) {
  (void)in_sizes; (void)n_in; (void)out_size;
  const float* inputs  = (const float*)d_in[0];
  const float* eco_Wk  = (const float*)d_in[1];
  const float* eco_Wr  = (const float*)d_in[2];
  const float* eco_b   = (const float*)d_in[3];
  const float* data_Wk = (const float*)d_in[4];
  const float* data_Wr = (const float*)d_in[5];
  const float* data_b  = (const float*)d_in[6];
  const float* att_Wk  = (const float*)d_in[7];
  const float* att_Wr  = (const float*)d_in[8];
  const float* att_b   = (const float*)d_in[9];
  const float* ts_Wk   = (const float*)d_in[10];
  const float* ts_Wr   = (const float*)d_in[11];
  const float* ts_b    = (const float*)d_in[12];
  const float* d1_W    = (const float*)d_in[13];
  const float* d1_b    = (const float*)d_in[14];
  const float* d2_W    = (const float*)d_in[15];
  const float* d2_b    = (const float*)d_in[16];
  const float* df_W    = (const float*)d_in[17];
  const float* df_b    = (const float*)d_in[18];

  char* ws = (char*)d_ws;
  size_t off = 0;
  auto take = [&](size_t bytes) -> void* {
    void* p = ws + off;
    off += (bytes + 255) & ~(size_t)255;
    return p;
  };
  unsigned short* wr_swz = (unsigned short*)take((size_t)22 * 262144 * 2);
  unsigned short* wk_da  = (unsigned short*)take((size_t)14 * 262144 * 2);
  unsigned short* wk_ts  = (unsigned short*)take((size_t)7  * 262144 * 2);
  unsigned short* xw_eco = (unsigned short*)take((size_t)TT * 65536 * 2);
  float*          h_last = (float*)take((size_t)7 * 16384 * 4);
  float*          d1o    = (float*)take((size_t)7 * 16384 * 4);
  // --- sync region (contiguous, memset each launch); sizes in 16B granules ---
  size_t sync_begin = off;
  u32x4* hE  = (u32x4*)take((size_t)RE * 4096 * 16);
  u32x4* hD  = (u32x4*)take((size_t)14 * 2 * 4096 * 16);
  u32x4* hsD = (u32x4*)take((size_t)7 * RS * 4096 * 16);
  u32x4* hsA = (u32x4*)take((size_t)7 * RS * 4096 * 16);
  u32x4* h2  = (u32x4*)take((size_t)7 * 2 * 4096 * 16);
  unsigned* hDf = (unsigned*)take(112 * 4);
  unsigned* h2f = (unsigned*)take(112 * 4);
  size_t sync_bytes = off - sync_begin;
  if (off > ws_size) return;   // fail loudly (output stays zero)

  hipMemsetAsync(ws + sync_begin, 0, sync_bytes, stream);
  k0a_wr<<<dim3(8, 8, 22), 256, 0, stream>>>(eco_Wr, data_Wr, att_Wr, ts_Wr, wr_swz);
  k0b_wk<<<dim3(4, 8, 21), 256, 0, stream>>>(data_Wk, att_Wk, ts_Wk, wk_da, wk_ts);
  k1_ecoxw<<<dim3(TT, 4), 256, 0, stream>>>(inputs, eco_Wk, eco_b, xw_eco);
  kP<<<240, 256, 0, stream>>>(wr_swz, wk_da, wk_ts, xw_eco, inputs,
                              data_Wk, att_Wk, data_b, att_b, ts_b,
                              hE, hD, hsD, hsA, h2, hDf, h2f, h_last);
  k7_d1<<<dim3(4, 7), 256, 0, stream>>>(h_last, d1_W, d1_b, d1o);
  k8_head<<<7, 256, 0, stream>>>(d1o, d2_W, d2_b, df_W, df_b, inputs, (float*)d_out);
}